// Round 15
// baseline (149.806 us; speedup 1.0000x reference)
//
#include <hip/hip_runtime.h>
#include <math.h>

constexpr int L_ = 2048, D_ = 128, H_ = 16;
constexpr int T_ = 8192;
constexpr int LDX = T_;              // col-major activations act[chan][token]

typedef __attribute__((ext_vector_type(8))) short short8;   // 8 bf16 (4 VGPR)
typedef __attribute__((ext_vector_type(4))) float floatx4;

// ---- static device globals ----
__device__ float g_qkv [3 * D_ * T_];       // col-major [384][8192]
__device__ unsigned short g_ctxH[T_ * D_];  // ctx bf16x2 ROW-major [t][128]
__device__ unsigned short g_ctxL[T_ * D_];
__device__ unsigned short g_Mf1H[D_ * D_];  // (W1*Wo) bf16x2 row-major [f][d]
__device__ unsigned short g_Mf1L[D_ * D_];
__device__ unsigned short g_MfcH[D_ * D_];  // (Wfc*W2) bf16x2 [o][f], o>=80 zero
__device__ unsigned short g_MfcL[D_ * D_];
__device__ float g_bf1 [D_];
__device__ float g_bfc [D_];

__device__ __forceinline__ unsigned short bf16h(float x) {      // RNE to bf16
    unsigned u = __float_as_uint(x);
    return (unsigned short)((u + 0x7FFFu + ((u >> 16) & 1u)) >> 16);
}
__device__ __forceinline__ float bf16f(unsigned short h) {
    return __uint_as_float(((unsigned)h) << 16);
}
__device__ __forceinline__ void unpack8(uint4 w, float* f) {    // 8 packed bf16
    unsigned a[4] = {w.x, w.y, w.z, w.w};
#pragma unroll
    for (int i = 0; i < 4; i++) {
        f[2 * i]     = __uint_as_float(a[i] << 16);
        f[2 * i + 1] = __uint_as_float(a[i] & 0xFFFF0000u);
    }
}

// ---------------------------------------------------------------------------
// stage1 (verbatim R14, proven): fused conv+qkv per 32-token tile + folds.
// grid 384 x 256.
// ---------------------------------------------------------------------------
__global__ __launch_bounds__(256) void stage1_kernel(
        const float* __restrict__ x, const float* __restrict__ conv_w,
        const float* __restrict__ conv_b,
        const float* __restrict__ bg, const float* __restrict__ bb,
        const float* __restrict__ brm, const float* __restrict__ brv,
        const float* __restrict__ in_proj_w, const float* __restrict__ in_proj_b,
        const float* __restrict__ out_w,  const float* __restrict__ out_b,
        const float* __restrict__ ff_w1,  const float* __restrict__ ff_b1,
        const float* __restrict__ ff_w2,  const float* __restrict__ ff_b2,
        const float* __restrict__ fc_w,   const float* __restrict__ fc_b) {
    __shared__ unsigned short sm[15360];          // 30 KB
    unsigned short* XsH = sm;                     // [32][104] (k padded 96)
    unsigned short* XsL = sm + 3328;
    unsigned short* HsH = sm + 6656;              // [32][136]
    unsigned short* HsL = sm + 11008;
    int bid = blockIdx.x, tid = threadIdx.x;

    if (bid < 256) {
        int t0 = bid * 32;

        for (int p = tid; p < 1280; p += 256) {
            int f0 = p * 2;
            int r = f0 / 80, k = f0 - r * 80;
            float2 v2 = *(const float2*)&x[(size_t)(t0 + r) * 80 + k];
            unsigned short h0 = bf16h(v2.x), h1 = bf16h(v2.y);
            *(unsigned*)&XsH[r * 104 + k] = (unsigned)h0 | ((unsigned)h1 << 16);
            *(unsigned*)&XsL[r * 104 + k] =
                (unsigned)bf16h(v2.x - bf16f(h0)) |
                ((unsigned)bf16h(v2.y - bf16f(h1)) << 16);
        }
        for (int i = tid; i < 384; i += 256) {
            int r = i / 12, k = 80 + 2 * (i - r * 12);
            *(unsigned*)&XsH[r * 104 + k] = 0u;
            *(unsigned*)&XsL[r * 104 + k] = 0u;
        }
        __syncthreads();

        int lane = tid & 63, w = tid >> 6;
        int m16 = lane & 15, quad = lane >> 4;

        short8 aH[2][3], aL[2][3];
#pragma unroll
        for (int mt = 0; mt < 2; mt++) {
            int c = w * 32 + mt * 16 + m16;
#pragma unroll
            for (int kt = 0; kt < 3; kt++) {
                int kb = kt * 32 + quad * 8;
                short8 vh = {0, 0, 0, 0, 0, 0, 0, 0};
                short8 vl = {0, 0, 0, 0, 0, 0, 0, 0};
                if (kb < 80) {
                    float4 f0 = *(const float4*)&conv_w[(size_t)c * 80 + kb];
                    float4 f1 = *(const float4*)&conv_w[(size_t)c * 80 + kb + 4];
                    float vv[8] = {f0.x, f0.y, f0.z, f0.w, f1.x, f1.y, f1.z, f1.w};
#pragma unroll
                    for (int e = 0; e < 8; e++) {
                        unsigned short hh = bf16h(vv[e]);
                        vh[e] = (short)hh;
                        vl[e] = (short)bf16h(vv[e] - bf16f(hh));
                    }
                }
                aH[mt][kt] = vh; aL[mt][kt] = vl;
            }
        }

#pragma unroll
        for (int mt = 0; mt < 2; mt++) {
#pragma unroll
            for (int nt = 0; nt < 2; nt++) {
                floatx4 acc = {0.f, 0.f, 0.f, 0.f};
                int trow = nt * 16 + m16;
#pragma unroll
                for (int kt = 0; kt < 3; kt++) {
                    short8 bHv = *(short8*)&XsH[trow * 104 + kt * 32 + quad * 8];
                    short8 bLv = *(short8*)&XsL[trow * 104 + kt * 32 + quad * 8];
                    acc = __builtin_amdgcn_mfma_f32_16x16x32_bf16(aH[mt][kt], bHv, acc, 0, 0, 0);
                    acc = __builtin_amdgcn_mfma_f32_16x16x32_bf16(aL[mt][kt], bHv, acc, 0, 0, 0);
                    acc = __builtin_amdgcn_mfma_f32_16x16x32_bf16(aH[mt][kt], bLv, acc, 0, 0, 0);
                }
                int c0 = w * 32 + mt * 16 + quad * 4;
                int t = t0 + nt * 16 + m16;
                int l = t & 2047;
                float vr[4];
#pragma unroll
                for (int r = 0; r < 4; r++) {
                    int c = c0 + r;
                    float v = acc[r] + conv_b[c];
                    v = fmaxf(v, 0.0f);
                    v = (v - brm[c]) * (bg[c] * rsqrtf(brv[c] + 1e-5f)) + bb[c];
                    float inv = __expf((float)(c >> 1) * (-9.210340371976184f / 128.0f));
                    float ang = (float)l * inv;
                    v += (c & 1) ? cosf(ang) : sinf(ang);
                    vr[r] = v;
                }
                unsigned short h0 = bf16h(vr[0]), h1 = bf16h(vr[1]);
                unsigned short h2 = bf16h(vr[2]), h3 = bf16h(vr[3]);
                unsigned hp[2] = {(unsigned)h0 | ((unsigned)h1 << 16),
                                  (unsigned)h2 | ((unsigned)h3 << 16)};
                unsigned lp[2] = {
                    (unsigned)bf16h(vr[0] - bf16f(h0)) | ((unsigned)bf16h(vr[1] - bf16f(h1)) << 16),
                    (unsigned)bf16h(vr[2] - bf16f(h2)) | ((unsigned)bf16h(vr[3] - bf16f(h3)) << 16)};
                int tl = nt * 16 + m16;
                *(uint2*)&HsH[tl * 136 + c0] = *(uint2*)hp;
                *(uint2*)&HsL[tl * 136 + c0] = *(uint2*)lp;
            }
        }
        __syncthreads();

#pragma unroll
        for (int ti = 0; ti < 6; ti++) {
            int c0 = w * 96 + ti * 16;
            short8 wH[4], wL[4];
#pragma unroll
            for (int kt = 0; kt < 4; kt++) {
                int kb = kt * 32 + quad * 8;
                float4 f0 = *(const float4*)&in_proj_w[(size_t)(c0 + m16) * 128 + kb];
                float4 f1 = *(const float4*)&in_proj_w[(size_t)(c0 + m16) * 128 + kb + 4];
                float vv[8] = {f0.x, f0.y, f0.z, f0.w, f1.x, f1.y, f1.z, f1.w};
                short8 vh, vl;
#pragma unroll
                for (int e = 0; e < 8; e++) {
                    unsigned short hh = bf16h(vv[e]);
                    vh[e] = (short)hh;
                    vl[e] = (short)bf16h(vv[e] - bf16f(hh));
                }
                wH[kt] = vh; wL[kt] = vl;
            }
            float bias_r[4];
#pragma unroll
            for (int r = 0; r < 4; r++) bias_r[r] = in_proj_b[c0 + quad * 4 + r];

#pragma unroll
            for (int s = 0; s < 2; s++) {
                floatx4 acc = {0.f, 0.f, 0.f, 0.f};
                int trow = s * 16 + m16;
#pragma unroll
                for (int kt = 0; kt < 4; kt++) {
                    short8 bH = *(short8*)&HsH[trow * 136 + kt * 32 + quad * 8];
                    short8 bL = *(short8*)&HsL[trow * 136 + kt * 32 + quad * 8];
                    acc = __builtin_amdgcn_mfma_f32_16x16x32_bf16(wH[kt], bH, acc, 0, 0, 0);
                    acc = __builtin_amdgcn_mfma_f32_16x16x32_bf16(wL[kt], bH, acc, 0, 0, 0);
                    acc = __builtin_amdgcn_mfma_f32_16x16x32_bf16(wH[kt], bL, acc, 0, 0, 0);
                }
#pragma unroll
                for (int r = 0; r < 4; r++)
                    g_qkv[(size_t)(c0 + quad * 4 + r) * LDX + t0 + s * 16 + m16] =
                        acc[r] + bias_r[r];
            }
        }
        return;
    }
    float* rowbuf = (float*)sm;                    // [2][128]
    float* red = (float*)sm + 256;                 // [256]
    if (bid < 320) {                               // ---- fold1 ----
        int sub = tid >> 7, k = tid & 127;
        int f = (bid - 256) * 2 + sub;
        rowbuf[sub * 128 + k] = ff_w1[f * 128 + k];
        __syncthreads();
        float acc = 0.f;
#pragma unroll 8
        for (int o = 0; o < 128; o++)
            acc = fmaf(rowbuf[sub * 128 + o], out_w[o * 128 + k], acc);
        unsigned short hi = bf16h(acc);
        g_Mf1H[f * 128 + k] = hi;
        g_Mf1L[f * 128 + k] = bf16h(acc - bf16f(hi));
        red[tid] = rowbuf[sub * 128 + k] * out_b[k];
        __syncthreads();
        for (int s = 64; s > 0; s >>= 1) {
            if (k < s) red[tid] += red[tid + s];
            __syncthreads();
        }
        if (k == 0) g_bf1[f] = red[sub * 128] + ff_b1[f];
        return;
    }
    {                                              // ---- fold2 ----
        int sub = tid >> 7, k = tid & 127;
        int o = (bid - 320) * 2 + sub;
        rowbuf[sub * 128 + k] = (o < 80) ? fc_w[o * 128 + k] : 0.f;
        __syncthreads();
        float acc = 0.f;
#pragma unroll 8
        for (int d = 0; d < 128; d++)
            acc = fmaf(rowbuf[sub * 128 + d], ff_w2[d * 128 + k], acc);
        unsigned short hi = bf16h(acc);
        g_MfcH[o * 128 + k] = hi;
        g_MfcL[o * 128 + k] = bf16h(acc - bf16f(hi));
        red[tid] = rowbuf[sub * 128 + k] * ff_b2[k];
        __syncthreads();
        for (int s = 64; s > 0; s >>= 1) {
            if (k < s) red[tid] += red[tid + s];
            __syncthreads();
        }
        if (k == 0) g_bfc[o] = (o < 80) ? (red[sub * 128] + fc_b[o]) : 0.f;
        return;
    }
}

// ---------------------------------------------------------------------------
// Attention full-window, packed-bf16 K/V staging: one slot = 8 ch x bf16 =
// 16 B = one ds_read_b128 (halves LDS reads vs fp32). Q stays fp32.
// Block = (bh, 512-q tile), 256 thr, 2 adjacent q/thread. grid (64, 4).
// ---------------------------------------------------------------------------
__global__ __launch_bounds__(256) void attn_kernel() {
    __shared__ uint4 SK16[2][324];                // [parity][idx], 8 bf16 each
    __shared__ uint4 SV16[2][324];
    int bh = blockIdx.x;
    int qb = blockIdx.y * 512;
    int b = bh >> 4, h = bh & 15;
    int tb = b * L_;
    int tid = threadIdx.x;
    int jbase = qb - 64;

    for (int c16 = 0; c16 < 16; c16++) {          // stage 16 ch x 641 slots
        int d = c16 & 7;
        int ch = ((c16 < 8) ? D_ : 2 * D_) + h * 8 + d;
        const float* src = g_qkv + (size_t)ch * LDX + tb;
        uint4* arr = (c16 < 8) ? &SK16[0][0] : &SV16[0][0];
        for (int s = tid; s < 641; s += 256) {
            int j = jbase + s;
            float v = ((unsigned)j < (unsigned)L_) ? src[j] : 0.f;
            ((unsigned short*)(arr + (s & 1) * 324 + (s >> 1)))[d] = bf16h(v);
        }
    }
    __syncthreads();

    const float sc = 0.35355339059327373f;        // 1/sqrt(8)
    int q0 = qb + 2 * tid;
    float qa[8], qc[8];
#pragma unroll
    for (int d = 0; d < 8; d++) {
        qa[d] = g_qkv[(size_t)(h * 8 + d) * LDX + tb + q0] * sc;
        qc[d] = g_qkv[(size_t)(h * 8 + d) * LDX + tb + q0 + 1] * sc;
    }
    float l0 = 0.f, l1 = 0.f;
    float A0[8] = {}, A1[8] = {};
    int j00 = jbase + 2 * tid;

#pragma unroll 2
    for (int it = 0; it <= 129; it++) {
        int pp = it & 1, idx = tid + (it >> 1);
        float kv[8];
        unpack8(SK16[pp][idx], kv);
        float s0 = 0.f, s1 = 0.f;
#pragma unroll
        for (int d = 0; d < 8; d++) {
            s0 = fmaf(qa[d], kv[d], s0);
            s1 = fmaf(qc[d], kv[d], s1);
        }
        bool jv = (unsigned)(j00 + it) < (unsigned)L_;
        float w0 = (jv && it != 64 && it <= 128) ? __expf(s0) : 0.f;
        float w1 = (jv && it != 65 && it >= 1)  ? __expf(s1) : 0.f;
        l0 += w0; l1 += w1;
        float vv[8];
        unpack8(SV16[pp][idx], vv);
#pragma unroll
        for (int d = 0; d < 8; d++) {
            A0[d] = fmaf(w0, vv[d], A0[d]);
            A1[d] = fmaf(w1, vv[d], A1[d]);
        }
    }
    float i0 = 1.f / l0, i1 = 1.f / l1;
    unsigned hp[4], lp[4];
#pragma unroll
    for (int d2 = 0; d2 < 4; d2++) {
        float v0 = A0[2 * d2] * i0, v1 = A0[2 * d2 + 1] * i0;
        unsigned short h0 = bf16h(v0), h1 = bf16h(v1);
        hp[d2] = (unsigned)h0 | ((unsigned)h1 << 16);
        lp[d2] = (unsigned)bf16h(v0 - bf16f(h0)) |
                 ((unsigned)bf16h(v1 - bf16f(h1)) << 16);
    }
    *(uint4*)&g_ctxH[(size_t)(tb + q0) * 128 + h * 8] = *(uint4*)hp;
    *(uint4*)&g_ctxL[(size_t)(tb + q0) * 128 + h * 8] = *(uint4*)lp;
#pragma unroll
    for (int d2 = 0; d2 < 4; d2++) {
        float v0 = A1[2 * d2] * i1, v1 = A1[2 * d2 + 1] * i1;
        unsigned short h0 = bf16h(v0), h1 = bf16h(v1);
        hp[d2] = (unsigned)h0 | ((unsigned)h1 << 16);
        lp[d2] = (unsigned)bf16h(v0 - bf16f(h0)) |
                 ((unsigned)bf16h(v1 - bf16f(h1)) << 16);
    }
    *(uint4*)&g_ctxH[(size_t)(tb + q0 + 1) * 128 + h * 8] = *(uint4*)hp;
    *(uint4*)&g_ctxL[(size_t)(tb + q0 + 1) * 128 + h * 8] = *(uint4*)lp;
}

// ---------------------------------------------------------------------------
// Fused tail via MFMA bf16x2 (verbatim R14, proven). 256 blocks.
// ---------------------------------------------------------------------------
__global__ __launch_bounds__(256) void f1fc_mfma(float* __restrict__ out) {
    __shared__ unsigned short sm[4 * 32 * 136];   // ctxH|ctxL|C1H|C1L
    unsigned short* ctxH = sm;
    unsigned short* ctxL = sm + 32 * 136;
    unsigned short* C1H  = sm + 2 * 32 * 136;
    unsigned short* C1L  = sm + 3 * 32 * 136;
    float* C2 = (float*)sm;
    __shared__ float b1s[128];

    int tid = threadIdx.x;
    int t0 = blockIdx.x * 32;

    for (int i = tid; i < 512; i += 256) {
        int r = i >> 4, c8 = (i & 15) * 8;
        *(uint4*)&ctxH[r * 136 + c8] = *(const uint4*)&g_ctxH[(size_t)(t0 + r) * 128 + c8];
        *(uint4*)&ctxL[r * 136 + c8] = *(const uint4*)&g_ctxL[(size_t)(t0 + r) * 128 + c8];
    }
    if (tid < 128) b1s[tid] = g_bf1[tid];
    __syncthreads();

    int lane = tid & 63, w = tid >> 6;
    int m16 = lane & 15, quad = lane >> 4;

    floatx4 acc1[2][2];
#pragma unroll
    for (int mt = 0; mt < 2; mt++) {
        int fbase = w * 32 + mt * 16 + m16;
        short8 aH[4], aL[4];
#pragma unroll
        for (int kt = 0; kt < 4; kt++) {
            aH[kt] = *(const short8*)&g_Mf1H[(size_t)fbase * 128 + kt * 32 + quad * 8];
            aL[kt] = *(const short8*)&g_Mf1L[(size_t)fbase * 128 + kt * 32 + quad * 8];
        }
#pragma unroll
        for (int nt = 0; nt < 2; nt++) {
            floatx4 acc = {0.f, 0.f, 0.f, 0.f};
            int trow = nt * 16 + m16;
#pragma unroll
            for (int kt = 0; kt < 4; kt++) {
                short8 bH = *(short8*)&ctxH[trow * 136 + kt * 32 + quad * 8];
                short8 bL = *(short8*)&ctxL[trow * 136 + kt * 32 + quad * 8];
                acc = __builtin_amdgcn_mfma_f32_16x16x32_bf16(aH[kt], bH, acc, 0, 0, 0);
                acc = __builtin_amdgcn_mfma_f32_16x16x32_bf16(aL[kt], bH, acc, 0, 0, 0);
                acc = __builtin_amdgcn_mfma_f32_16x16x32_bf16(aH[kt], bL, acc, 0, 0, 0);
            }
            acc1[mt][nt] = acc;
        }
    }
#pragma unroll
    for (int mt = 0; mt < 2; mt++) {
#pragma unroll
        for (int nt = 0; nt < 2; nt++) {
            int f0 = w * 32 + mt * 16 + quad * 4;
            int t = nt * 16 + m16;
            float v[4];
#pragma unroll
            for (int r = 0; r < 4; r++)
                v[r] = fmaxf(acc1[mt][nt][r] + b1s[f0 + r], 0.f);
            unsigned short h0 = bf16h(v[0]), h1 = bf16h(v[1]);
            unsigned short h2 = bf16h(v[2]), h3 = bf16h(v[3]);
            *(unsigned*)&C1H[t * 136 + f0]     = (unsigned)h0 | ((unsigned)h1 << 16);
            *(unsigned*)&C1H[t * 136 + f0 + 2] = (unsigned)h2 | ((unsigned)h3 << 16);
            *(unsigned*)&C1L[t * 136 + f0] =
                (unsigned)bf16h(v[0] - bf16f(h0)) | ((unsigned)bf16h(v[1] - bf16f(h1)) << 16);
            *(unsigned*)&C1L[t * 136 + f0 + 2] =
                (unsigned)bf16h(v[2] - bf16f(h2)) | ((unsigned)bf16h(v[3] - bf16f(h3)) << 16);
        }
    }
    __syncthreads();

    floatx4 acc2[2][2];
#pragma unroll
    for (int mt = 0; mt < 2; mt++) {
        int obase = w * 32 + mt * 16 + m16;
        short8 aH[4], aL[4];
#pragma unroll
        for (int kt = 0; kt < 4; kt++) {
            aH[kt] = *(const short8*)&g_MfcH[(size_t)obase * 128 + kt * 32 + quad * 8];
            aL[kt] = *(const short8*)&g_MfcL[(size_t)obase * 128 + kt * 32 + quad * 8];
        }
#pragma unroll
        for (int nt = 0; nt < 2; nt++) {
            floatx4 acc = {0.f, 0.f, 0.f, 0.f};
            int trow = nt * 16 + m16;
#pragma unroll
            for (int kt = 0; kt < 4; kt++) {
                short8 bH = *(short8*)&C1H[trow * 136 + kt * 32 + quad * 8];
                short8 bL = *(short8*)&C1L[trow * 136 + kt * 32 + quad * 8];
                acc = __builtin_amdgcn_mfma_f32_16x16x32_bf16(aH[kt], bH, acc, 0, 0, 0);
                acc = __builtin_amdgcn_mfma_f32_16x16x32_bf16(aL[kt], bH, acc, 0, 0, 0);
                acc = __builtin_amdgcn_mfma_f32_16x16x32_bf16(aH[kt], bL, acc, 0, 0, 0);
            }
            acc2[mt][nt] = acc;
        }
    }
    __syncthreads();
#pragma unroll
    for (int mt = 0; mt < 2; mt++) {
        int o0 = w * 32 + mt * 16 + quad * 4;
        if (o0 < 96) {
#pragma unroll
            for (int nt = 0; nt < 2; nt++) {
                int t = nt * 16 + m16;
#pragma unroll
                for (int r = 0; r < 4; r++)
                    C2[t * 100 + o0 + r] = acc2[mt][nt][r] + g_bfc[o0 + r];
            }
        }
    }
    __syncthreads();
    for (int i = tid; i < 640; i += 256) {
        int t = i / 20, c4 = i - t * 20;
        *(float4*)&out[(size_t)(t0 + t) * 80 + c4 * 4] = *(float4*)&C2[t * 100 + c4 * 4];
    }
}

// ---------------------------------------------------------------------------
extern "C" void kernel_launch(void* const* d_in, const int* in_sizes, int n_in,
                              void* d_out, int out_size, void* d_ws, size_t ws_size,
                              hipStream_t stream) {
    const float* x         = (const float*)d_in[0];
    const float* conv_w    = (const float*)d_in[1];
    const float* conv_b    = (const float*)d_in[2];
    const float* bn_g      = (const float*)d_in[3];
    const float* bn_b      = (const float*)d_in[4];
    const float* bn_rm     = (const float*)d_in[5];
    const float* bn_rv     = (const float*)d_in[6];
    const float* in_proj_w = (const float*)d_in[7];
    const float* in_proj_b = (const float*)d_in[8];
    const float* out_w     = (const float*)d_in[9];
    const float* out_b     = (const float*)d_in[10];
    const float* ff_w1     = (const float*)d_in[11];
    const float* ff_b1     = (const float*)d_in[12];
    const float* ff_w2     = (const float*)d_in[13];
    const float* ff_b2     = (const float*)d_in[14];
    const float* fc_w      = (const float*)d_in[15];
    const float* fc_b      = (const float*)d_in[16];

    // fused conv+qkv + folds, one dispatch
    stage1_kernel<<<384, 256, 0, stream>>>(x, conv_w, conv_b, bn_g, bn_b,
                                           bn_rm, bn_rv, in_proj_w, in_proj_b,
                                           out_w, out_b, ff_w1, ff_b1,
                                           ff_w2, ff_b2, fc_w, fc_b);

    // full-window attention (packed-bf16 K/V) -> ctx bf16x2: 256 blocks
    attn_kernel<<<dim3(64, 4), 256, 0, stream>>>();

    // fused MFMA tail -> row-major [t][80]: 256 blocks
    f1fc_mfma<<<256, 256, 0, stream>>>((float*)d_out);
}

// Round 16
// 146.755 us; speedup vs baseline: 1.0208x; 1.0208x over previous
//
#include <hip/hip_runtime.h>
#include <math.h>

constexpr int L_ = 2048, D_ = 128, H_ = 16;
constexpr int T_ = 8192;
constexpr int LDX = T_;              // col-major activations act[chan][token]

typedef __attribute__((ext_vector_type(8))) short short8;   // 8 bf16 (4 VGPR)
typedef __attribute__((ext_vector_type(4))) float floatx4;

// ---- static device globals ----
__device__ float g_qkv [3 * D_ * T_];       // col-major [384][8192]
__device__ unsigned short g_ctxH[T_ * D_];  // ctx bf16x2 ROW-major [t][128]
__device__ unsigned short g_ctxL[T_ * D_];
__device__ unsigned short g_Mf1H[D_ * D_];  // (W1*Wo) bf16x2 row-major [f][d]
__device__ unsigned short g_Mf1L[D_ * D_];
__device__ unsigned short g_MfcH[D_ * D_];  // (Wfc*W2) bf16x2 [o][f], o>=80 zero
__device__ unsigned short g_MfcL[D_ * D_];
__device__ float g_bf1 [D_];
__device__ float g_bfc [D_];

__device__ __forceinline__ unsigned short bf16h(float x) {      // RNE to bf16
    unsigned u = __float_as_uint(x);
    return (unsigned short)((u + 0x7FFFu + ((u >> 16) & 1u)) >> 16);
}
__device__ __forceinline__ float bf16f(unsigned short h) {
    return __uint_as_float(((unsigned)h) << 16);
}

// ---------------------------------------------------------------------------
// stage1 (verbatim R14, proven): fused conv+qkv per 32-token tile + folds.
// grid 384 x 256.
// ---------------------------------------------------------------------------
__global__ __launch_bounds__(256) void stage1_kernel(
        const float* __restrict__ x, const float* __restrict__ conv_w,
        const float* __restrict__ conv_b,
        const float* __restrict__ bg, const float* __restrict__ bb,
        const float* __restrict__ brm, const float* __restrict__ brv,
        const float* __restrict__ in_proj_w, const float* __restrict__ in_proj_b,
        const float* __restrict__ out_w,  const float* __restrict__ out_b,
        const float* __restrict__ ff_w1,  const float* __restrict__ ff_b1,
        const float* __restrict__ ff_w2,  const float* __restrict__ ff_b2,
        const float* __restrict__ fc_w,   const float* __restrict__ fc_b) {
    __shared__ unsigned short sm[15360];          // 30 KB
    unsigned short* XsH = sm;                     // [32][104] (k padded 96)
    unsigned short* XsL = sm + 3328;
    unsigned short* HsH = sm + 6656;              // [32][136]
    unsigned short* HsL = sm + 11008;
    int bid = blockIdx.x, tid = threadIdx.x;

    if (bid < 256) {
        int t0 = bid * 32;

        for (int p = tid; p < 1280; p += 256) {
            int f0 = p * 2;
            int r = f0 / 80, k = f0 - r * 80;
            float2 v2 = *(const float2*)&x[(size_t)(t0 + r) * 80 + k];
            unsigned short h0 = bf16h(v2.x), h1 = bf16h(v2.y);
            *(unsigned*)&XsH[r * 104 + k] = (unsigned)h0 | ((unsigned)h1 << 16);
            *(unsigned*)&XsL[r * 104 + k] =
                (unsigned)bf16h(v2.x - bf16f(h0)) |
                ((unsigned)bf16h(v2.y - bf16f(h1)) << 16);
        }
        for (int i = tid; i < 384; i += 256) {
            int r = i / 12, k = 80 + 2 * (i - r * 12);
            *(unsigned*)&XsH[r * 104 + k] = 0u;
            *(unsigned*)&XsL[r * 104 + k] = 0u;
        }
        __syncthreads();

        int lane = tid & 63, w = tid >> 6;
        int m16 = lane & 15, quad = lane >> 4;

        short8 aH[2][3], aL[2][3];
#pragma unroll
        for (int mt = 0; mt < 2; mt++) {
            int c = w * 32 + mt * 16 + m16;
#pragma unroll
            for (int kt = 0; kt < 3; kt++) {
                int kb = kt * 32 + quad * 8;
                short8 vh = {0, 0, 0, 0, 0, 0, 0, 0};
                short8 vl = {0, 0, 0, 0, 0, 0, 0, 0};
                if (kb < 80) {
                    float4 f0 = *(const float4*)&conv_w[(size_t)c * 80 + kb];
                    float4 f1 = *(const float4*)&conv_w[(size_t)c * 80 + kb + 4];
                    float vv[8] = {f0.x, f0.y, f0.z, f0.w, f1.x, f1.y, f1.z, f1.w};
#pragma unroll
                    for (int e = 0; e < 8; e++) {
                        unsigned short hh = bf16h(vv[e]);
                        vh[e] = (short)hh;
                        vl[e] = (short)bf16h(vv[e] - bf16f(hh));
                    }
                }
                aH[mt][kt] = vh; aL[mt][kt] = vl;
            }
        }

#pragma unroll
        for (int mt = 0; mt < 2; mt++) {
#pragma unroll
            for (int nt = 0; nt < 2; nt++) {
                floatx4 acc = {0.f, 0.f, 0.f, 0.f};
                int trow = nt * 16 + m16;
#pragma unroll
                for (int kt = 0; kt < 3; kt++) {
                    short8 bHv = *(short8*)&XsH[trow * 104 + kt * 32 + quad * 8];
                    short8 bLv = *(short8*)&XsL[trow * 104 + kt * 32 + quad * 8];
                    acc = __builtin_amdgcn_mfma_f32_16x16x32_bf16(aH[mt][kt], bHv, acc, 0, 0, 0);
                    acc = __builtin_amdgcn_mfma_f32_16x16x32_bf16(aL[mt][kt], bHv, acc, 0, 0, 0);
                    acc = __builtin_amdgcn_mfma_f32_16x16x32_bf16(aH[mt][kt], bLv, acc, 0, 0, 0);
                }
                int c0 = w * 32 + mt * 16 + quad * 4;
                int t = t0 + nt * 16 + m16;
                int l = t & 2047;
                float vr[4];
#pragma unroll
                for (int r = 0; r < 4; r++) {
                    int c = c0 + r;
                    float v = acc[r] + conv_b[c];
                    v = fmaxf(v, 0.0f);
                    v = (v - brm[c]) * (bg[c] * rsqrtf(brv[c] + 1e-5f)) + bb[c];
                    float inv = __expf((float)(c >> 1) * (-9.210340371976184f / 128.0f));
                    float ang = (float)l * inv;
                    v += (c & 1) ? cosf(ang) : sinf(ang);
                    vr[r] = v;
                }
                unsigned short h0 = bf16h(vr[0]), h1 = bf16h(vr[1]);
                unsigned short h2 = bf16h(vr[2]), h3 = bf16h(vr[3]);
                unsigned hp[2] = {(unsigned)h0 | ((unsigned)h1 << 16),
                                  (unsigned)h2 | ((unsigned)h3 << 16)};
                unsigned lp[2] = {
                    (unsigned)bf16h(vr[0] - bf16f(h0)) | ((unsigned)bf16h(vr[1] - bf16f(h1)) << 16),
                    (unsigned)bf16h(vr[2] - bf16f(h2)) | ((unsigned)bf16h(vr[3] - bf16f(h3)) << 16)};
                int tl = nt * 16 + m16;
                *(uint2*)&HsH[tl * 136 + c0] = *(uint2*)hp;
                *(uint2*)&HsL[tl * 136 + c0] = *(uint2*)lp;
            }
        }
        __syncthreads();

#pragma unroll
        for (int ti = 0; ti < 6; ti++) {
            int c0 = w * 96 + ti * 16;
            short8 wH[4], wL[4];
#pragma unroll
            for (int kt = 0; kt < 4; kt++) {
                int kb = kt * 32 + quad * 8;
                float4 f0 = *(const float4*)&in_proj_w[(size_t)(c0 + m16) * 128 + kb];
                float4 f1 = *(const float4*)&in_proj_w[(size_t)(c0 + m16) * 128 + kb + 4];
                float vv[8] = {f0.x, f0.y, f0.z, f0.w, f1.x, f1.y, f1.z, f1.w};
                short8 vh, vl;
#pragma unroll
                for (int e = 0; e < 8; e++) {
                    unsigned short hh = bf16h(vv[e]);
                    vh[e] = (short)hh;
                    vl[e] = (short)bf16h(vv[e] - bf16f(hh));
                }
                wH[kt] = vh; wL[kt] = vl;
            }
            float bias_r[4];
#pragma unroll
            for (int r = 0; r < 4; r++) bias_r[r] = in_proj_b[c0 + quad * 4 + r];

#pragma unroll
            for (int s = 0; s < 2; s++) {
                floatx4 acc = {0.f, 0.f, 0.f, 0.f};
                int trow = s * 16 + m16;
#pragma unroll
                for (int kt = 0; kt < 4; kt++) {
                    short8 bH = *(short8*)&HsH[trow * 136 + kt * 32 + quad * 8];
                    short8 bL = *(short8*)&HsL[trow * 136 + kt * 32 + quad * 8];
                    acc = __builtin_amdgcn_mfma_f32_16x16x32_bf16(wH[kt], bH, acc, 0, 0, 0);
                    acc = __builtin_amdgcn_mfma_f32_16x16x32_bf16(wL[kt], bH, acc, 0, 0, 0);
                    acc = __builtin_amdgcn_mfma_f32_16x16x32_bf16(wH[kt], bL, acc, 0, 0, 0);
                }
#pragma unroll
                for (int r = 0; r < 4; r++)
                    g_qkv[(size_t)(c0 + quad * 4 + r) * LDX + t0 + s * 16 + m16] =
                        acc[r] + bias_r[r];
            }
        }
        return;
    }
    float* rowbuf = (float*)sm;                    // [2][128]
    float* red = (float*)sm + 256;                 // [256]
    if (bid < 320) {                               // ---- fold1 ----
        int sub = tid >> 7, k = tid & 127;
        int f = (bid - 256) * 2 + sub;
        rowbuf[sub * 128 + k] = ff_w1[f * 128 + k];
        __syncthreads();
        float acc = 0.f;
#pragma unroll 8
        for (int o = 0; o < 128; o++)
            acc = fmaf(rowbuf[sub * 128 + o], out_w[o * 128 + k], acc);
        unsigned short hi = bf16h(acc);
        g_Mf1H[f * 128 + k] = hi;
        g_Mf1L[f * 128 + k] = bf16h(acc - bf16f(hi));
        red[tid] = rowbuf[sub * 128 + k] * out_b[k];
        __syncthreads();
        for (int s = 64; s > 0; s >>= 1) {
            if (k < s) red[tid] += red[tid + s];
            __syncthreads();
        }
        if (k == 0) g_bf1[f] = red[sub * 128] + ff_b1[f];
        return;
    }
    {                                              // ---- fold2 ----
        int sub = tid >> 7, k = tid & 127;
        int o = (bid - 320) * 2 + sub;
        rowbuf[sub * 128 + k] = (o < 80) ? fc_w[o * 128 + k] : 0.f;
        __syncthreads();
        float acc = 0.f;
#pragma unroll 8
        for (int d = 0; d < 128; d++)
            acc = fmaf(rowbuf[sub * 128 + d], ff_w2[d * 128 + k], acc);
        unsigned short hi = bf16h(acc);
        g_MfcH[o * 128 + k] = hi;
        g_MfcL[o * 128 + k] = bf16h(acc - bf16f(hi));
        red[tid] = rowbuf[sub * 128 + k] * ff_b2[k];
        __syncthreads();
        for (int s = 64; s > 0; s >>= 1) {
            if (k < s) red[tid] += red[tid + s];
            __syncthreads();
        }
        if (k == 0) g_bfc[o] = (o < 80) ? (red[sub * 128] + fc_b[o]) : 0.f;
        return;
    }
}

// ---------------------------------------------------------------------------
// Attention full-window (verbatim R13/R14 champion, fp32 parity-split K/V),
// -> ctx bf16x2 row-major. Block = (bh, 512-q tile), 256 thr. grid (64, 4).
// ---------------------------------------------------------------------------
__global__ __launch_bounds__(256) void attn_kernel() {
    __shared__ float4 SK[2][2][324];
    __shared__ float4 SV[2][2][324];
    int bh = blockIdx.x;
    int qb = blockIdx.y * 512;
    int b = bh >> 4, h = bh & 15;
    int tb = b * L_;
    int tid = threadIdx.x;
    int jbase = qb - 64;

    for (int c16 = 0; c16 < 16; c16++) {
        int d = c16 & 7;
        int ch = ((c16 < 8) ? D_ : 2 * D_) + h * 8 + d;
        const float* src = g_qkv + (size_t)ch * LDX + tb;
        float4* base4 = ((c16 < 8) ? &SK[0][0][0] : &SV[0][0][0]) + (d >> 2) * 324;
        for (int s = tid; s < 641; s += 256) {
            int j = jbase + s;
            float v = ((unsigned)j < (unsigned)L_) ? src[j] : 0.f;
            ((float*)(base4 + (s & 1) * 648 + (s >> 1)))[d & 3] = v;
        }
    }
    __syncthreads();

    const float sc = 0.35355339059327373f;      // 1/sqrt(8)
    int q0 = qb + 2 * tid;
    float qa[8], qc[8];
#pragma unroll
    for (int d = 0; d < 8; d++) {
        qa[d] = g_qkv[(size_t)(h * 8 + d) * LDX + tb + q0] * sc;
        qc[d] = g_qkv[(size_t)(h * 8 + d) * LDX + tb + q0 + 1] * sc;
    }
    float l0 = 0.f, l1 = 0.f;
    float A0[8] = {}, A1[8] = {};
    int j00 = jbase + 2 * tid;

#pragma unroll 2
    for (int it = 0; it <= 129; it++) {
        int pp = it & 1, idx = tid + (it >> 1);
        float4 ka = SK[pp][0][idx], kb2 = SK[pp][1][idx];
        float kv[8] = {ka.x, ka.y, ka.z, ka.w, kb2.x, kb2.y, kb2.z, kb2.w};
        float s0 = 0.f, s1 = 0.f;
#pragma unroll
        for (int d = 0; d < 8; d++) {
            s0 = fmaf(qa[d], kv[d], s0);
            s1 = fmaf(qc[d], kv[d], s1);
        }
        bool jv = (unsigned)(j00 + it) < (unsigned)L_;
        float w0 = (jv && it != 64 && it <= 128) ? __expf(s0) : 0.f;
        float w1 = (jv && it != 65 && it >= 1)  ? __expf(s1) : 0.f;
        l0 += w0; l1 += w1;
        float4 va = SV[pp][0][idx], vb2 = SV[pp][1][idx];
        float vv[8] = {va.x, va.y, va.z, va.w, vb2.x, vb2.y, vb2.z, vb2.w};
#pragma unroll
        for (int d = 0; d < 8; d++) {
            A0[d] = fmaf(w0, vv[d], A0[d]);
            A1[d] = fmaf(w1, vv[d], A1[d]);
        }
    }
    float i0 = 1.f / l0, i1 = 1.f / l1;
    unsigned hp[4], lp[4];
#pragma unroll
    for (int d2 = 0; d2 < 4; d2++) {
        float v0 = A0[2 * d2] * i0, v1 = A0[2 * d2 + 1] * i0;
        unsigned short h0 = bf16h(v0), h1 = bf16h(v1);
        hp[d2] = (unsigned)h0 | ((unsigned)h1 << 16);
        lp[d2] = (unsigned)bf16h(v0 - bf16f(h0)) |
                 ((unsigned)bf16h(v1 - bf16f(h1)) << 16);
    }
    *(uint4*)&g_ctxH[(size_t)(tb + q0) * 128 + h * 8] = *(uint4*)hp;
    *(uint4*)&g_ctxL[(size_t)(tb + q0) * 128 + h * 8] = *(uint4*)lp;
#pragma unroll
    for (int d2 = 0; d2 < 4; d2++) {
        float v0 = A1[2 * d2] * i1, v1 = A1[2 * d2 + 1] * i1;
        unsigned short h0 = bf16h(v0), h1 = bf16h(v1);
        hp[d2] = (unsigned)h0 | ((unsigned)h1 << 16);
        lp[d2] = (unsigned)bf16h(v0 - bf16f(h0)) |
                 ((unsigned)bf16h(v1 - bf16f(h1)) << 16);
    }
    *(uint4*)&g_ctxH[(size_t)(tb + q0 + 1) * 128 + h * 8] = *(uint4*)hp;
    *(uint4*)&g_ctxL[(size_t)(tb + q0 + 1) * 128 + h * 8] = *(uint4*)lp;
}

// ---------------------------------------------------------------------------
// Fused tail via MFMA bf16x2 (verbatim R14, proven). 256 blocks.
// ---------------------------------------------------------------------------
__global__ __launch_bounds__(256) void f1fc_mfma(float* __restrict__ out) {
    __shared__ unsigned short sm[4 * 32 * 136];   // ctxH|ctxL|C1H|C1L
    unsigned short* ctxH = sm;
    unsigned short* ctxL = sm + 32 * 136;
    unsigned short* C1H  = sm + 2 * 32 * 136;
    unsigned short* C1L  = sm + 3 * 32 * 136;
    float* C2 = (float*)sm;
    __shared__ float b1s[128];

    int tid = threadIdx.x;
    int t0 = blockIdx.x * 32;

    for (int i = tid; i < 512; i += 256) {
        int r = i >> 4, c8 = (i & 15) * 8;
        *(uint4*)&ctxH[r * 136 + c8] = *(const uint4*)&g_ctxH[(size_t)(t0 + r) * 128 + c8];
        *(uint4*)&ctxL[r * 136 + c8] = *(const uint4*)&g_ctxL[(size_t)(t0 + r) * 128 + c8];
    }
    if (tid < 128) b1s[tid] = g_bf1[tid];
    __syncthreads();

    int lane = tid & 63, w = tid >> 6;
    int m16 = lane & 15, quad = lane >> 4;

    floatx4 acc1[2][2];
#pragma unroll
    for (int mt = 0; mt < 2; mt++) {
        int fbase = w * 32 + mt * 16 + m16;
        short8 aH[4], aL[4];
#pragma unroll
        for (int kt = 0; kt < 4; kt++) {
            aH[kt] = *(const short8*)&g_Mf1H[(size_t)fbase * 128 + kt * 32 + quad * 8];
            aL[kt] = *(const short8*)&g_Mf1L[(size_t)fbase * 128 + kt * 32 + quad * 8];
        }
#pragma unroll
        for (int nt = 0; nt < 2; nt++) {
            floatx4 acc = {0.f, 0.f, 0.f, 0.f};
            int trow = nt * 16 + m16;
#pragma unroll
            for (int kt = 0; kt < 4; kt++) {
                short8 bH = *(short8*)&ctxH[trow * 136 + kt * 32 + quad * 8];
                short8 bL = *(short8*)&ctxL[trow * 136 + kt * 32 + quad * 8];
                acc = __builtin_amdgcn_mfma_f32_16x16x32_bf16(aH[kt], bH, acc, 0, 0, 0);
                acc = __builtin_amdgcn_mfma_f32_16x16x32_bf16(aL[kt], bH, acc, 0, 0, 0);
                acc = __builtin_amdgcn_mfma_f32_16x16x32_bf16(aH[kt], bL, acc, 0, 0, 0);
            }
            acc1[mt][nt] = acc;
        }
    }
#pragma unroll
    for (int mt = 0; mt < 2; mt++) {
#pragma unroll
        for (int nt = 0; nt < 2; nt++) {
            int f0 = w * 32 + mt * 16 + quad * 4;
            int t = nt * 16 + m16;
            float v[4];
#pragma unroll
            for (int r = 0; r < 4; r++)
                v[r] = fmaxf(acc1[mt][nt][r] + b1s[f0 + r], 0.f);
            unsigned short h0 = bf16h(v[0]), h1 = bf16h(v[1]);
            unsigned short h2 = bf16h(v[2]), h3 = bf16h(v[3]);
            *(unsigned*)&C1H[t * 136 + f0]     = (unsigned)h0 | ((unsigned)h1 << 16);
            *(unsigned*)&C1H[t * 136 + f0 + 2] = (unsigned)h2 | ((unsigned)h3 << 16);
            *(unsigned*)&C1L[t * 136 + f0] =
                (unsigned)bf16h(v[0] - bf16f(h0)) | ((unsigned)bf16h(v[1] - bf16f(h1)) << 16);
            *(unsigned*)&C1L[t * 136 + f0 + 2] =
                (unsigned)bf16h(v[2] - bf16f(h2)) | ((unsigned)bf16h(v[3] - bf16f(h3)) << 16);
        }
    }
    __syncthreads();

    floatx4 acc2[2][2];
#pragma unroll
    for (int mt = 0; mt < 2; mt++) {
        int obase = w * 32 + mt * 16 + m16;
        short8 aH[4], aL[4];
#pragma unroll
        for (int kt = 0; kt < 4; kt++) {
            aH[kt] = *(const short8*)&g_MfcH[(size_t)obase * 128 + kt * 32 + quad * 8];
            aL[kt] = *(const short8*)&g_MfcL[(size_t)obase * 128 + kt * 32 + quad * 8];
        }
#pragma unroll
        for (int nt = 0; nt < 2; nt++) {
            floatx4 acc = {0.f, 0.f, 0.f, 0.f};
            int trow = nt * 16 + m16;
#pragma unroll
            for (int kt = 0; kt < 4; kt++) {
                short8 bH = *(short8*)&C1H[trow * 136 + kt * 32 + quad * 8];
                short8 bL = *(short8*)&C1L[trow * 136 + kt * 32 + quad * 8];
                acc = __builtin_amdgcn_mfma_f32_16x16x32_bf16(aH[kt], bH, acc, 0, 0, 0);
                acc = __builtin_amdgcn_mfma_f32_16x16x32_bf16(aL[kt], bH, acc, 0, 0, 0);
                acc = __builtin_amdgcn_mfma_f32_16x16x32_bf16(aH[kt], bL, acc, 0, 0, 0);
            }
            acc2[mt][nt] = acc;
        }
    }
    __syncthreads();
#pragma unroll
    for (int mt = 0; mt < 2; mt++) {
        int o0 = w * 32 + mt * 16 + quad * 4;
        if (o0 < 96) {
#pragma unroll
            for (int nt = 0; nt < 2; nt++) {
                int t = nt * 16 + m16;
#pragma unroll
                for (int r = 0; r < 4; r++)
                    C2[t * 100 + o0 + r] = acc2[mt][nt][r] + g_bfc[o0 + r];
            }
        }
    }
    __syncthreads();
    for (int i = tid; i < 640; i += 256) {
        int t = i / 20, c4 = i - t * 20;
        *(float4*)&out[(size_t)(t0 + t) * 80 + c4 * 4] = *(float4*)&C2[t * 100 + c4 * 4];
    }
}

// ---------------------------------------------------------------------------
extern "C" void kernel_launch(void* const* d_in, const int* in_sizes, int n_in,
                              void* d_out, int out_size, void* d_ws, size_t ws_size,
                              hipStream_t stream) {
    const float* x         = (const float*)d_in[0];
    const float* conv_w    = (const float*)d_in[1];
    const float* conv_b    = (const float*)d_in[2];
    const float* bn_g      = (const float*)d_in[3];
    const float* bn_b      = (const float*)d_in[4];
    const float* bn_rm     = (const float*)d_in[5];
    const float* bn_rv     = (const float*)d_in[6];
    const float* in_proj_w = (const float*)d_in[7];
    const float* in_proj_b = (const float*)d_in[8];
    const float* out_w     = (const float*)d_in[9];
    const float* out_b     = (const float*)d_in[10];
    const float* ff_w1     = (const float*)d_in[11];
    const float* ff_b1     = (const float*)d_in[12];
    const float* ff_w2     = (const float*)d_in[13];
    const float* ff_b2     = (const float*)d_in[14];
    const float* fc_w      = (const float*)d_in[15];
    const float* fc_b      = (const float*)d_in[16];

    // fused conv+qkv + folds, one dispatch
    stage1_kernel<<<384, 256, 0, stream>>>(x, conv_w, conv_b, bn_g, bn_b,
                                           bn_rm, bn_rv, in_proj_w, in_proj_b,
                                           out_w, out_b, ff_w1, ff_b1,
                                           ff_w2, ff_b2, fc_w, fc_b);

    // full-window attention (fp32 parity-split K/V) -> ctx bf16x2: 256 blocks
    attn_kernel<<<dim3(64, 4), 256, 0, stream>>>();

    // fused MFMA tail -> row-major [t][80]: 256 blocks
    f1fc_mfma<<<256, 256, 0, stream>>>((float*)d_out);
}